// Round 8
// baseline (395.080 us; speedup 1.0000x reference)
//
#include <hip/hip_runtime.h>

// VQ-VAE forward: x [64,64,32,32] f32 (NCHW, C==D), weight [512,64] f32.
// d_out: loss (1) | q_out (4194304, NCHW) | encodings (33554432, [N,K]).
//
// R8 = R7 + explicit software pipeline. R7 diagnosis: acc[8][8] (128 regs,
// irreducible: E/O dual chains are correctness-critical) + launch_bounds(,2)
// forced 2 waves/SIMD with no load prefetch -> per-step ds/vmem latency fully
// exposed (VALUBusy 44%). Fix: 1-dp register double-buffer (load dp+1's 4 LDS
// x-frags + 4 VMEM w-frags before the 64 pk_fma of dp), launch_bounds(256,1)
// so the ~220-reg working set allocates without acc shuffling. Arithmetic and
// tie order identical to R7 (passing).

#define NROWS 65536
#define DIM 64
#define KCODES 512
#define HW 1024
#define TPB 256
#define RPB 64                      // rows per block
#define NBLOCKS (NROWS / RPB)       // 1024
#define NW 4

// d_ws float offsets
#define WT_OFF 0                    // wTp [32 dpair][512 k][2] = 32768 floats
#define E2_OFF 32768                // e2 [512]
#define X2_OFF 33280                // x2 [65536]
#define PART_OFF 98816              // partials [1024]

typedef float v2f __attribute__((ext_vector_type(2)));
typedef float v4f __attribute__((ext_vector_type(4)));

// xs layout: per dpair plane (32 planes): 8 chunks of 8 rows (v2f each);
// chunk pitch 20 floats -> the 8 rg lanes hit 8 distinct bank groups;
// plane pitch 160 floats. Total 20480 B.
#define XS_IDX(dp, row) ((dp) * 160 + ((row) >> 3) * 20 + ((row) & 7) * 2)

__global__ __launch_bounds__(256) void vq_prep(
    const float* __restrict__ x, const float* __restrict__ w,
    float* __restrict__ ws)
{
    const int bid = blockIdx.x, t = threadIdx.x;
    if (bid < 2) {
        // w -> wTp[dpair][k][2] (E,O interleave) + e2 (ascending-d chain)
        const int k = bid * 256 + t;
        float s = 0.0f;
        for (int d = 0; d < DIM; ++d) {
            const float v = w[k * DIM + d];
            ws[WT_OFF + (d >> 1) * (KCODES * 2) + k * 2 + (d & 1)] = v;
            s = __fadd_rn(s, __fmul_rn(v, v));
        }
        ws[E2_OFF + k] = s;
    } else {
        // x2 per row, coalesced
        const int n = (bid - 2) * 256 + t;
        const int b = n >> 10, hw = n & 1023;
        const float* xr = x + (size_t)b * DIM * HW + hw;
        float s = 0.0f;
        for (int d = 0; d < DIM; ++d) {
            const float v = xr[(size_t)d * HW];
            s = __fadd_rn(s, __fmul_rn(v, v));
        }
        ws[X2_OFF + n] = s;
    }
}

__global__ __launch_bounds__(TPB, 1) void vq_main(
    const float* __restrict__ x, const float* __restrict__ w,
    const float* __restrict__ ws, float* __restrict__ out,
    float* __restrict__ partial)
{
    __shared__ __align__(16) float xs[32 * 160];   // 20480 B
    __shared__ float bestw[NW][RPB];
    __shared__ int   bidxw[NW][RPB];
    __shared__ int   idxf[RPB];
    __shared__ float lred[NW];

    const int t    = threadIdx.x;
    const int lane = t & 63;
    const int wv   = __builtin_amdgcn_readfirstlane(t >> 6);
    const int rg   = lane & 7;        // rows rg*8 .. rg*8+7
    const int kg   = lane >> 3;       // 8 codes per kit
    const int n0   = blockIdx.x * RPB;
    const int b    = n0 >> 10;        // no b straddle (1024 % 64 == 0)
    const int hw0  = n0 & 1023;

    // ---- stage x tile into LDS, (E,O) interleaved per dpair.
    {
        const int row4 = (t & 15) * 4;
        #pragma unroll
        for (int p = 0; p < 2; ++p) {
            const int dp = p * 16 + (t >> 4);
            const float* pe = x + (size_t)b * DIM * HW
                              + (size_t)(2 * dp) * HW + hw0 + row4;
            const v4f xe = *(const v4f*)pe;          // 4 rows, even depth
            const v4f xo = *(const v4f*)(pe + HW);   // 4 rows, odd depth
            const v4f o0 = {xe.x, xo.x, xe.y, xo.y};
            const v4f o1 = {xe.z, xo.z, xe.w, xo.w};
            float* dst = xs + XS_IDX(dp, row4);
            *(v4f*)dst       = o0;
            *(v4f*)(dst + 4) = o1;
        }
    }

    const v4f x2a = *(const v4f*)(ws + X2_OFF + n0 + rg * 8);
    const v4f x2b = *(const v4f*)(ws + X2_OFF + n0 + rg * 8 + 4);

    __syncthreads();

    const float* wT  = ws + WT_OFF;
    const float* e2p = ws + E2_OFF;

    float best[8];
    int   bidx[8];
    #pragma unroll
    for (int r = 0; r < 8; ++r) { best[r] = 3.4e38f; bidx[r] = 0; }

    const int xls = rg * 20;          // lane's float offset within a plane

    #pragma unroll 1
    for (int kit = 0; kit < 2; ++kit) {
        const int kb = wv * 128 + kit * 64 + kg * 8;   // lane's 8 codes
        v2f acc[8][8];
        #pragma unroll
        for (int r = 0; r < 8; ++r)
            #pragma unroll
            for (int c = 0; c < 8; ++c) acc[r][c] = (v2f){0.f, 0.f};

        const float* wp = wT + (size_t)kb * 2;
        const float* xp = xs + xls;

        // prologue: load dp=0 into current buffers
        v4f Xc0 = *(const v4f*)(xp);
        v4f Xc1 = *(const v4f*)(xp + 4);
        v4f Xc2 = *(const v4f*)(xp + 8);
        v4f Xc3 = *(const v4f*)(xp + 12);
        v4f Wc0 = *(const v4f*)(wp);
        v4f Wc1 = *(const v4f*)(wp + 4);
        v4f Wc2 = *(const v4f*)(wp + 8);
        v4f Wc3 = *(const v4f*)(wp + 12);

        #pragma unroll
        for (int dp = 0; dp < 32; ++dp) {
            // prefetch dp+1 (clamped: last iter re-loads dp=31, discarded)
            const int dpn = (dp < 31) ? dp + 1 : 31;
            const float* xq = xp + dpn * 160;
            const float* wq = wp + (size_t)dpn * (KCODES * 2);
            const v4f Xn0 = *(const v4f*)(xq);
            const v4f Xn1 = *(const v4f*)(xq + 4);
            const v4f Xn2 = *(const v4f*)(xq + 8);
            const v4f Xn3 = *(const v4f*)(xq + 12);
            const v4f Wn0 = *(const v4f*)(wq);
            const v4f Wn1 = *(const v4f*)(wq + 4);
            const v4f Wn2 = *(const v4f*)(wq + 8);
            const v4f Wn3 = *(const v4f*)(wq + 12);

            const v2f xr[8] = {Xc0.xy, Xc0.zw, Xc1.xy, Xc1.zw,
                               Xc2.xy, Xc2.zw, Xc3.xy, Xc3.zw};
            const v2f wc[8] = {Wc0.xy, Wc0.zw, Wc1.xy, Wc1.zw,
                               Wc2.xy, Wc2.zw, Wc3.xy, Wc3.zw};
            #pragma unroll
            for (int r = 0; r < 8; ++r)
                #pragma unroll
                for (int c = 0; c < 8; ++c)
                    acc[r][c] += xr[r] * wc[c];      // v_pk_fma_f32 (E,O)

            Xc0 = Xn0; Xc1 = Xn1; Xc2 = Xn2; Xc3 = Xn3;
            Wc0 = Wn0; Wc1 = Wn1; Wc2 = Wn2; Wc3 = Wn3;
        }

        const v4f e20 = *(const v4f*)(e2p + kb);
        const v4f e21 = *(const v4f*)(e2p + kb + 4);
        #pragma unroll
        for (int r = 0; r < 8; ++r) {
            const float x2r = (r < 4) ? x2a[r] : x2b[r - 4];
            #pragma unroll
            for (int c = 0; c < 8; ++c) {            // c ascending: first-min
                const float dot  = acc[r][c][0] + acc[r][c][1];   // E + O
                const float e2c  = (c < 4) ? e20[c] : e21[c - 4];
                const float dist = __fsub_rn(__fadd_rn(x2r, e2c),
                                             __fmul_rn(2.0f, dot));
                if (dist < best[r]) { best[r] = dist; bidx[r] = kb + c; }
            }
        }
    }

    // ---- butterfly argmin over kg; explicit lowest-index tie-break.
    #pragma unroll
    for (int m = 8; m <= 32; m <<= 1) {
        #pragma unroll
        for (int r = 0; r < 8; ++r) {
            const float ob = __shfl_xor(best[r], m, 64);
            const int   oi = __shfl_xor(bidx[r], m, 64);
            if (ob < best[r] || (ob == best[r] && oi < bidx[r])) {
                best[r] = ob; bidx[r] = oi;
            }
        }
    }
    if (lane < 8) {                   // rg == lane: rows lane*8..+7
        #pragma unroll
        for (int r = 0; r < 8; ++r) {
            bestw[wv][lane * 8 + r] = best[r];
            bidxw[wv][lane * 8 + r] = bidx[r];
        }
    }
    __syncthreads();

    // ---- cross-wave argmin; explicit lowest-index tie-break.
    if (t < RPB) {
        float bb = bestw[0][t];
        int   bi = bidxw[0][t];
        #pragma unroll
        for (int v = 1; v < NW; ++v) {
            const float c  = bestw[v][t];
            const int   ci = bidxw[v][t];
            if (c < bb || (c == bb && ci < bi)) { bb = c; bi = ci; }
        }
        idxf[t] = bi;
    }
    __syncthreads();

    // ---- epilogue: q gather/store + loss. thread = (row rt, d-group dg).
    const int rt = t & 63;
    const int dg = t >> 6;            // 4 groups x 16 d
    const int widx = idxf[rt];
    const float* wrow = w + widx * DIM + dg * 16;
    const float* xrow = x + (size_t)b * DIM * HW + hw0 + rt;
    float* q = out + 1;
    float lsum = 0.0f;
    #pragma unroll
    for (int j = 0; j < 16; ++j) {
        const int d = dg * 16 + j;
        const float wvv = wrow[j];                    // per-lane gather, L1-hot
        const float xd  = xrow[(size_t)d * HW];
        const float df  = __fsub_rn(wvv, xd);
        lsum = __fadd_rn(lsum, __fmul_rn(df, df));
        q[(size_t)(b * DIM + d) * HW + hw0 + rt] = wvv;   // coalesced per d
    }

    #pragma unroll
    for (int off = 32; off; off >>= 1) lsum += __shfl_down(lsum, off, 64);
    if (lane == 0) lred[wv] = lsum;
    __syncthreads();
    if (t == 0) {
        float s = 0.0f;
        #pragma unroll
        for (int v = 0; v < NW; ++v) s += lred[v];
        partial[blockIdx.x] = s;
    }

    // ---- encodings: direct compute, aligned float4 middle
    // (slab global float index == 1 mod 4 -> peel 3, tail 1).
    float* slab = out + 1 + (size_t)NROWS * DIM + (size_t)n0 * KCODES;
    if (t < 3) slab[t] = (idxf[0] == t) ? 1.0f : 0.0f;
    if (t == 4) slab[RPB * KCODES - 1] = (idxf[RPB - 1] == 511) ? 1.0f : 0.0f;
    {
        v4f* s4 = (v4f*)(slab + 3);                   // 16B-aligned
        const int nf4 = (RPB * KCODES - 4) / 4;       // 8191
        for (int f = t; f < nf4; f += TPB) {
            const int ii = 3 + 4 * f;
            v4f o;
            #pragma unroll
            for (int c = 0; c < 4; ++c) {
                const int e = ii + c;
                o[c] = (idxf[e >> 9] == (e & 511)) ? 1.0f : 0.0f;
            }
            s4[f] = o;
        }
    }
}

__global__ __launch_bounds__(256) void vq_final(
    const float* __restrict__ partial, float* __restrict__ out)
{
    __shared__ float s[256];
    const int t = threadIdx.x;
    s[t] = (partial[t] + partial[t + 256]) + (partial[t + 512] + partial[t + 768]);
    __syncthreads();
    for (int off = 128; off; off >>= 1) {
        if (t < off) s[t] += s[t + off];
        __syncthreads();
    }
    if (t == 0) {
        const float m = s[0] / 4194304.0f;            // mean over B*H*W*D
        out[0] = __fadd_rn(m, __fmul_rn(0.25f, m));   // z_q + 0.25*z_e
    }
}

extern "C" void kernel_launch(void* const* d_in, const int* in_sizes, int n_in,
                              void* d_out, int out_size, void* d_ws, size_t ws_size,
                              hipStream_t stream) {
    const float* x = (const float*)d_in[0];
    const float* w = (const float*)d_in[1];
    float* out     = (float*)d_out;
    float* ws      = (float*)d_ws;

    vq_prep<<<258, 256, 0, stream>>>(x, w, ws);
    vq_main<<<NBLOCKS, TPB, 0, stream>>>(x, w, ws, out, ws + PART_OFF);
    vq_final<<<1, 256, 0, stream>>>(ws + PART_OFF, out);
}

// Round 9
// 217.833 us; speedup vs baseline: 1.8137x; 1.8137x over previous
//
#include <hip/hip_runtime.h>

// VQ-VAE forward: x [64,64,32,32] f32 (NCHW, C==D), weight [512,64] f32.
// d_out: loss (1) | q_out (4194304, NCHW) | encodings (33554432, [N,K]).
//
// R9: both operands in LDS. Block = 128 rows; 4 waves SPLIT ROWS (32 each) so
// every row's full 512-code argmin completes in one wave (no cross-wave
// merge). Codes in 4 chunks of 128; w chunk staged to LDS per chunk (barrier,
// reg-copy). x tile unpadded 32KB (x-reads 2-way bank-aliased = free, m136);
// w padded 20-float kg-pitch (unpadded would be 8-way). 74.3KB LDS -> dynamic
// + hipFuncSetAttribute, 2 blocks/CU. Per dp step: 8 ds_read_b128 -> 64
// pk_fma (R7's exact inner-loop source structure; VGPR ~R7's 128+temps, no
// R8-style prefetch regs -> no spill). Arithmetic + tie order identical to
// R6/R7: chunk-ascending k per lane, strict <, explicit lowest-index
// tie-break in the kg butterfly.

#define NROWS 65536
#define DIM 64
#define KCODES 512
#define HW 1024
#define TPB 256
#define RPB 128                     // rows per block
#define NBLOCKS (NROWS / RPB)       // 512

// d_ws float offsets
#define WT_OFF 0                    // wTp [32 dpair][512 k][2] = 32768 floats
#define E2_OFF 32768                // e2 [512]
#define X2_OFF 33280                // x2 [65536]
#define PART_OFF 98816              // partials [512]

// dynamic LDS float offsets
#define XW 8192                     // xs: 8192 floats (32 dp x 128 rows x E/O)
#define DYN_FLOATS (XW + 32 * 320)  // + w chunk 32 dp x (16 kg x 20) = 18432
#define DYN_BYTES (DYN_FLOATS * 4)  // 73728 B

typedef float v2f __attribute__((ext_vector_type(2)));
typedef float v4f __attribute__((ext_vector_type(4)));

__global__ __launch_bounds__(256) void vq_prep(
    const float* __restrict__ x, const float* __restrict__ w,
    float* __restrict__ ws)
{
    const int bid = blockIdx.x, t = threadIdx.x;
    if (bid < 2) {
        // w -> wTp[dpair][k][2] (E,O interleave) + e2 (ascending-d chain)
        const int k = bid * 256 + t;
        float s = 0.0f;
        for (int d = 0; d < DIM; ++d) {
            const float v = w[k * DIM + d];
            ws[WT_OFF + (d >> 1) * (KCODES * 2) + k * 2 + (d & 1)] = v;
            s = __fadd_rn(s, __fmul_rn(v, v));
        }
        ws[E2_OFF + k] = s;
    } else {
        // x2 per row, coalesced
        const int n = (bid - 2) * 256 + t;
        const int b = n >> 10, hw = n & 1023;
        const float* xr = x + (size_t)b * DIM * HW + hw;
        float s = 0.0f;
        for (int d = 0; d < DIM; ++d) {
            const float v = xr[(size_t)d * HW];
            s = __fadd_rn(s, __fmul_rn(v, v));
        }
        ws[X2_OFF + n] = s;
    }
}

__global__ __launch_bounds__(TPB) void vq_main(
    const float* __restrict__ x, const float* __restrict__ w,
    const float* __restrict__ ws, float* __restrict__ out,
    float* __restrict__ partial)
{
    extern __shared__ __align__(16) float smem[];   // [XW) = xs, [XW..) = wl
    __shared__ int   idxf[RPB];
    __shared__ float lred[4];

    const int t    = threadIdx.x;
    const int lane = t & 63;
    const int wv   = __builtin_amdgcn_readfirstlane(t >> 6);
    const int rg   = lane >> 4;       // 0..3: rows wv*32 + rg*8 .. +7
    const int kg   = lane & 15;       // 16 groups x 8 codes = 128 chunk codes
    const int n0   = blockIdx.x * RPB;
    const int b    = n0 >> 10;        // 1024 % 128 == 0: no b straddle
    const int hw0  = n0 & 1023;

    // ---- stage x tile (128 rows) into LDS, (E,O) interleaved, UNPADDED:
    // xs[dp*256 + (row>>3)*16 + (row&7)*2 (+1 for odd d)]
    #pragma unroll
    for (int i = 0; i < 4; ++i) {
        const int task = i * 256 + t;          // 1024 tasks
        const int dp   = task >> 5;
        const int row4 = (task & 31) * 4;
        const float* pe = x + (size_t)(b * DIM + 2 * dp) * HW + hw0 + row4;
        const v4f xe = *(const v4f*)pe;        // 4 rows, even depth
        const v4f xo = *(const v4f*)(pe + HW); // 4 rows, odd depth
        float* dst = smem + dp * 256 + (row4 >> 3) * 16 + (row4 & 7) * 2;
        *(v4f*)dst       = (v4f){xe.x, xo.x, xe.y, xo.y};
        *(v4f*)(dst + 4) = (v4f){xe.z, xo.z, xe.w, xo.w};
    }

    const int rowb = n0 + wv * 32 + rg * 8;    // this lane's first row
    const v4f x2a = *(const v4f*)(ws + X2_OFF + rowb);
    const v4f x2b = *(const v4f*)(ws + X2_OFF + rowb + 4);

    const float* e2p = ws + E2_OFF;
    const int cj = wv * 4 + rg;                // x row-chunk id (0..15)

    float best[8];
    int   bidx[8];
    #pragma unroll
    for (int r = 0; r < 8; ++r) { best[r] = 3.4e38f; bidx[r] = 0; }

    // ---- 4 chunks of 128 codes, ascending (=> per-lane k ascending)
    #pragma unroll 1
    for (int c = 0; c < 4; ++c) {
        // stage w chunk c: wTp[dp][c*128..+128][2] -> wl[dp*320 + kg*20 + j*2]
        v4f wstg[8];
        const float* src = ws + WT_OFF + c * 256;
        #pragma unroll
        for (int i = 0; i < 8; ++i) {
            const int s = i * 1024 + t * 4;
            wstg[i] = *(const v4f*)(src + (s >> 8) * 1024 + (s & 255));
        }
        __syncthreads();   // c=0: xs writes done; c>0: prev chunk reads done
        #pragma unroll
        for (int i = 0; i < 8; ++i) {
            const int s   = i * 1024 + t * 4;
            const int dp  = s >> 8;
            const int lc0 = (s & 255) >> 1;    // even -> 16B-aligned dst
            *(v4f*)(smem + XW + dp * 320 + (lc0 >> 3) * 20 + (lc0 & 7) * 2)
                = wstg[i];
        }
        __syncthreads();

        v2f acc[8][8];
        #pragma unroll
        for (int r = 0; r < 8; ++r)
            #pragma unroll
            for (int cc = 0; cc < 8; ++cc) acc[r][cc] = (v2f){0.f, 0.f};

        const float* xp = smem + cj * 16;
        const float* wp = smem + XW + kg * 20;
        #pragma unroll 4
        for (int dp = 0; dp < 32; ++dp) {
            const v4f X0 = *(const v4f*)(xp);        // rows 0,1 (E,O) pairs
            const v4f X1 = *(const v4f*)(xp + 4);    // rows 2,3
            const v4f X2 = *(const v4f*)(xp + 8);    // rows 4,5
            const v4f X3 = *(const v4f*)(xp + 12);   // rows 6,7
            const v4f W0 = *(const v4f*)(wp);        // codes 0,1 (E,O) pairs
            const v4f W1 = *(const v4f*)(wp + 4);    // codes 2,3
            const v4f W2 = *(const v4f*)(wp + 8);    // codes 4,5
            const v4f W3 = *(const v4f*)(wp + 12);   // codes 6,7
            const v2f xr[8] = {X0.xy, X0.zw, X1.xy, X1.zw,
                               X2.xy, X2.zw, X3.xy, X3.zw};
            const v2f wc[8] = {W0.xy, W0.zw, W1.xy, W1.zw,
                               W2.xy, W2.zw, W3.xy, W3.zw};
            #pragma unroll
            for (int r = 0; r < 8; ++r)
                #pragma unroll
                for (int cc = 0; cc < 8; ++cc)
                    acc[r][cc] += xr[r] * wc[cc];    // v_pk_fma_f32 (E,O)
            xp += 256;
            wp += 320;
        }

        const int kb = c * 128 + kg * 8;             // lane's 8 codes
        const v4f e20 = *(const v4f*)(e2p + kb);
        const v4f e21 = *(const v4f*)(e2p + kb + 4);
        #pragma unroll
        for (int r = 0; r < 8; ++r) {
            const float x2r = (r < 4) ? x2a[r] : x2b[r - 4];
            #pragma unroll
            for (int cc = 0; cc < 8; ++cc) {         // cc ascending: first-min
                const float dot  = acc[r][cc][0] + acc[r][cc][1];   // E + O
                const float e2c  = (cc < 4) ? e20[cc] : e21[cc - 4];
                const float dist = __fsub_rn(__fadd_rn(x2r, e2c),
                                             __fmul_rn(2.0f, dot));
                if (dist < best[r]) { best[r] = dist; bidx[r] = kb + cc; }
            }
        }
    }

    // ---- kg butterfly (16 lanes); explicit lowest-index tie-break
    #pragma unroll
    for (int m = 1; m <= 8; m <<= 1) {
        #pragma unroll
        for (int r = 0; r < 8; ++r) {
            const float ob = __shfl_xor(best[r], m, 64);
            const int   oi = __shfl_xor(bidx[r], m, 64);
            if (ob < best[r] || (ob == best[r] && oi < bidx[r])) {
                best[r] = ob; bidx[r] = oi;
            }
        }
    }
    if (kg == 0) {
        #pragma unroll
        for (int r = 0; r < 8; ++r)
            idxf[wv * 32 + rg * 8 + r] = bidx[r];
    }
    __syncthreads();

    // ---- epilogue: q gather/store + loss. thread = (row rt, d-group dg).
    const int rt = t & 127;
    const int dg = t >> 7;            // 2 groups x 32 d
    const int widx = idxf[rt];
    const float* wrow = w + widx * DIM + dg * 32;
    const float* xrow = x + (size_t)b * DIM * HW + hw0 + rt;
    float* q = out + 1;
    float lsum = 0.0f;
    #pragma unroll
    for (int j = 0; j < 32; ++j) {
        const int d = dg * 32 + j;
        const float wvv = wrow[j];                    // per-lane gather, L1-hot
        const float xd  = xrow[(size_t)d * HW];
        const float df  = __fsub_rn(wvv, xd);
        lsum = __fadd_rn(lsum, __fmul_rn(df, df));
        q[(size_t)(b * DIM + d) * HW + hw0 + rt] = wvv;   // coalesced per d
    }

    #pragma unroll
    for (int off = 32; off; off >>= 1) lsum += __shfl_down(lsum, off, 64);
    if (lane == 0) lred[wv] = lsum;
    __syncthreads();
    if (t == 0)
        partial[blockIdx.x] = (lred[0] + lred[1]) + (lred[2] + lred[3]);

    // ---- encodings: direct compute, aligned float4 middle
    // (slab global float index == 1 mod 4 -> peel 3, tail 1).
    float* slab = out + 1 + (size_t)NROWS * DIM + (size_t)n0 * KCODES;
    if (t < 3) slab[t] = (idxf[0] == t) ? 1.0f : 0.0f;
    if (t == 4) slab[RPB * KCODES - 1] = (idxf[RPB - 1] == 511) ? 1.0f : 0.0f;
    {
        v4f* s4 = (v4f*)(slab + 3);                   // 16B-aligned
        const int nf4 = (RPB * KCODES - 4) / 4;       // 16383
        for (int f = t; f < nf4; f += TPB) {
            const int ii = 3 + 4 * f;
            v4f o;
            #pragma unroll
            for (int cc = 0; cc < 4; ++cc) {
                const int e = ii + cc;
                o[cc] = (idxf[e >> 9] == (e & 511)) ? 1.0f : 0.0f;
            }
            s4[f] = o;
        }
    }
}

__global__ __launch_bounds__(256) void vq_final(
    const float* __restrict__ partial, float* __restrict__ out)
{
    __shared__ float s[256];
    const int t = threadIdx.x;
    s[t] = partial[t] + partial[t + 256];
    __syncthreads();
    for (int off = 128; off; off >>= 1) {
        if (t < off) s[t] += s[t + off];
        __syncthreads();
    }
    if (t == 0) {
        const float m = s[0] / 4194304.0f;            // mean over B*H*W*D
        out[0] = __fadd_rn(m, __fmul_rn(0.25f, m));   // z_q + 0.25*z_e
    }
}

extern "C" void kernel_launch(void* const* d_in, const int* in_sizes, int n_in,
                              void* d_out, int out_size, void* d_ws, size_t ws_size,
                              hipStream_t stream) {
    const float* x = (const float*)d_in[0];
    const float* w = (const float*)d_in[1];
    float* out     = (float*)d_out;
    float* ws      = (float*)d_ws;

    // 73728 B dynamic LDS > 64 KB default limit: opt in (idempotent, host-side,
    // graph-capture-safe — not a stream op).
    (void)hipFuncSetAttribute((const void*)vq_main,
                              hipFuncAttributeMaxDynamicSharedMemorySize,
                              DYN_BYTES);

    vq_prep<<<258, 256, 0, stream>>>(x, w, ws);
    vq_main<<<NBLOCKS, TPB, DYN_BYTES, stream>>>(x, w, ws, out, ws + PART_OFF);
    vq_final<<<1, 256, 0, stream>>>(ws + PART_OFF, out);
}

// Round 10
// 216.464 us; speedup vs baseline: 1.8252x; 1.0063x over previous
//
#include <hip/hip_runtime.h>

// VQ-VAE forward: x [64,64,32,32] f32 (NCHW, C==D), weight [512,64] f32.
// d_out: loss (1) | q_out (4194304, NCHW) | encodings (33554432, [N,K]).
//
// R10 = R9 (both operands in LDS, 4 waves split 128 rows, 4 code-chunks) +
// serial-latency removal:
//  - x2 computed in-kernel from the staged LDS x tile (identical ascending-d
//    chain); prep shrinks to 2 blocks (w transpose + e2 only)
//  - w chunk c+1 prefetched into staging regs during chunk c compute
//    (regs: acc 128 + wnext 32 + frags ~40 < 256; NOT R8's per-dp prefetch)
//  - epilogue loss/q reads x from LDS instead of global (same chain order)
// Dist arithmetic + tie order bit-identical to R6/R7/R9 (passing).

#define NROWS 65536
#define DIM 64
#define KCODES 512
#define HW 1024
#define TPB 256
#define RPB 128                     // rows per block
#define NBLOCKS (NROWS / RPB)       // 512

// d_ws float offsets
#define WT_OFF 0                    // wTp [32 dpair][512 k][2] = 32768 floats
#define E2_OFF 32768                // e2 [512]
#define PART_OFF 98816              // partials [512]

// dynamic LDS float offsets
#define XW 8192                     // xs: 32 dp x 128 rows x (E,O)
#define DYN_FLOATS (XW + 32 * 320)  // + w chunk 32 dp x (16 kg x 20) = 18432
#define DYN_BYTES (DYN_FLOATS * 4)  // 73728 B

typedef float v2f __attribute__((ext_vector_type(2)));
typedef float v4f __attribute__((ext_vector_type(4)));

__global__ __launch_bounds__(256) void vq_prep(
    const float* __restrict__ w, float* __restrict__ ws)
{
    // w -> wTp[dpair][k][2] (E,O interleave) + e2 (ascending-d chain)
    const int k = blockIdx.x * 256 + threadIdx.x;
    float s = 0.0f;
    for (int d = 0; d < DIM; ++d) {
        const float v = w[k * DIM + d];
        ws[WT_OFF + (d >> 1) * (KCODES * 2) + k * 2 + (d & 1)] = v;
        s = __fadd_rn(s, __fmul_rn(v, v));
    }
    ws[E2_OFF + k] = s;
}

__global__ __launch_bounds__(TPB) void vq_main(
    const float* __restrict__ x, const float* __restrict__ w,
    const float* __restrict__ ws, float* __restrict__ out,
    float* __restrict__ partial)
{
    extern __shared__ __align__(16) float smem[];   // [0,XW)=xs, [XW..)=wl
    __shared__ int   idxf[RPB];
    __shared__ float x2l[RPB];
    __shared__ float lred[4];

    const int t    = threadIdx.x;
    const int lane = t & 63;
    const int wv   = __builtin_amdgcn_readfirstlane(t >> 6);
    const int rg   = lane >> 4;       // 0..3: rows wv*32 + rg*8 .. +7
    const int kg   = lane & 15;       // 16 groups x 8 codes per chunk
    const int n0   = blockIdx.x * RPB;
    const int b    = n0 >> 10;        // 1024 % 128 == 0: no b straddle
    const int hw0  = n0 & 1023;

    // ---- prefetch w chunk 0 into staging regs (independent of xs staging)
    v4f wstg[8];
    {
        const float* src = ws + WT_OFF;
        #pragma unroll
        for (int i = 0; i < 8; ++i) {
            const int s = i * 1024 + t * 4;
            wstg[i] = *(const v4f*)(src + (s >> 8) * 1024 + (s & 255));
        }
    }

    // ---- stage x tile (128 rows) into LDS, (E,O) interleaved, unpadded:
    // xs[dp*256 + (row>>3)*16 + (row&7)*2 (+1 for odd d)]
    #pragma unroll
    for (int i = 0; i < 4; ++i) {
        const int task = i * 256 + t;          // 1024 tasks
        const int dp   = task >> 5;
        const int row4 = (task & 31) * 4;
        const float* pe = x + (size_t)(b * DIM + 2 * dp) * HW + hw0 + row4;
        const v4f xe = *(const v4f*)pe;        // 4 rows, even depth
        const v4f xo = *(const v4f*)(pe + HW); // 4 rows, odd depth
        float* dst = smem + dp * 256 + (row4 >> 3) * 16 + (row4 & 7) * 2;
        *(v4f*)dst       = (v4f){xe.x, xo.x, xe.y, xo.y};
        *(v4f*)(dst + 4) = (v4f){xe.z, xo.z, xe.w, xo.w};
    }
    __syncthreads();   // xs visible

    // ---- x2 per row from LDS: same ascending-d mul-then-add chain as prep's
    if (t < RPB) {
        const float* xb = smem + (t >> 3) * 16 + (t & 7) * 2;
        float s = 0.0f;
        #pragma unroll 8
        for (int dp = 0; dp < 32; ++dp) {
            const v2f p = *(const v2f*)(xb + dp * 256);   // (E,O) of d=2dp
            s = __fadd_rn(s, __fmul_rn(p[0], p[0]));
            s = __fadd_rn(s, __fmul_rn(p[1], p[1]));
        }
        x2l[t] = s;
    }

    // ---- write w chunk 0 to LDS; prefetch chunk 1
    #pragma unroll
    for (int i = 0; i < 8; ++i) {
        const int s   = i * 1024 + t * 4;
        const int dp  = s >> 8;
        const int lc0 = (s & 255) >> 1;
        *(v4f*)(smem + XW + dp * 320 + (lc0 >> 3) * 20 + (lc0 & 7) * 2)
            = wstg[i];
    }
    {
        const float* src = ws + WT_OFF + 256;
        #pragma unroll
        for (int i = 0; i < 8; ++i) {
            const int s = i * 1024 + t * 4;
            wstg[i] = *(const v4f*)(src + (s >> 8) * 1024 + (s & 255));
        }
    }
    __syncthreads();   // x2l + w chunk 0 visible

    const float* e2p = ws + E2_OFF;
    const int cj = wv * 4 + rg;                // x row-chunk id (0..15)
    const int rloc = wv * 32 + rg * 8;         // first row (block-local)
    const v4f x2a = *(const v4f*)(x2l + rloc);
    const v4f x2b = *(const v4f*)(x2l + rloc + 4);

    float best[8];
    int   bidx[8];
    #pragma unroll
    for (int r = 0; r < 8; ++r) { best[r] = 3.4e38f; bidx[r] = 0; }

    // ---- 4 chunks of 128 codes, ascending (=> per-lane k ascending)
    #pragma unroll 1
    for (int c = 0; c < 4; ++c) {
        v2f acc[8][8];
        #pragma unroll
        for (int r = 0; r < 8; ++r)
            #pragma unroll
            for (int cc = 0; cc < 8; ++cc) acc[r][cc] = (v2f){0.f, 0.f};

        const float* xp = smem + cj * 16;
        const float* wp = smem + XW + kg * 20;
        #pragma unroll 4
        for (int dp = 0; dp < 32; ++dp) {
            const v4f X0 = *(const v4f*)(xp);        // rows 0,1 (E,O) pairs
            const v4f X1 = *(const v4f*)(xp + 4);    // rows 2,3
            const v4f X2 = *(const v4f*)(xp + 8);    // rows 4,5
            const v4f X3 = *(const v4f*)(xp + 12);   // rows 6,7
            const v4f W0 = *(const v4f*)(wp);        // codes 0,1 (E,O) pairs
            const v4f W1 = *(const v4f*)(wp + 4);    // codes 2,3
            const v4f W2 = *(const v4f*)(wp + 8);    // codes 4,5
            const v4f W3 = *(const v4f*)(wp + 12);   // codes 6,7
            const v2f xr[8] = {X0.xy, X0.zw, X1.xy, X1.zw,
                               X2.xy, X2.zw, X3.xy, X3.zw};
            const v2f wc[8] = {W0.xy, W0.zw, W1.xy, W1.zw,
                               W2.xy, W2.zw, W3.xy, W3.zw};
            #pragma unroll
            for (int r = 0; r < 8; ++r)
                #pragma unroll
                for (int cc = 0; cc < 8; ++cc)
                    acc[r][cc] += xr[r] * wc[cc];    // v_pk_fma_f32 (E,O)
            xp += 256;
            wp += 320;
        }

        const int kb = c * 128 + kg * 8;             // lane's 8 codes
        const v4f e20 = *(const v4f*)(e2p + kb);
        const v4f e21 = *(const v4f*)(e2p + kb + 4);
        #pragma unroll
        for (int r = 0; r < 8; ++r) {
            const float x2r = (r < 4) ? x2a[r] : x2b[r - 4];
            #pragma unroll
            for (int cc = 0; cc < 8; ++cc) {         // cc ascending: first-min
                const float dot  = acc[r][cc][0] + acc[r][cc][1];   // E + O
                const float e2c  = (cc < 4) ? e20[cc] : e21[cc - 4];
                const float dist = __fsub_rn(__fadd_rn(x2r, e2c),
                                             __fmul_rn(2.0f, dot));
                if (dist < best[r]) { best[r] = dist; bidx[r] = kb + cc; }
            }
        }

        if (c < 3) {
            __syncthreads();   // all reads of w chunk c done
            #pragma unroll
            for (int i = 0; i < 8; ++i) {            // write chunk c+1
                const int s   = i * 1024 + t * 4;
                const int dp  = s >> 8;
                const int lc0 = (s & 255) >> 1;
                *(v4f*)(smem + XW + dp * 320 + (lc0 >> 3) * 20
                        + (lc0 & 7) * 2) = wstg[i];
            }
            if (c < 2) {                             // prefetch chunk c+2
                const float* src = ws + WT_OFF + (c + 2) * 256;
                #pragma unroll
                for (int i = 0; i < 8; ++i) {
                    const int s = i * 1024 + t * 4;
                    wstg[i] = *(const v4f*)(src + (s >> 8) * 1024 + (s & 255));
                }
            }
            __syncthreads();   // chunk c+1 visible
        }
    }

    // ---- kg butterfly (16 lanes); explicit lowest-index tie-break
    #pragma unroll
    for (int m = 1; m <= 8; m <<= 1) {
        #pragma unroll
        for (int r = 0; r < 8; ++r) {
            const float ob = __shfl_xor(best[r], m, 64);
            const int   oi = __shfl_xor(bidx[r], m, 64);
            if (ob < best[r] || (ob == best[r] && oi < bidx[r])) {
                best[r] = ob; bidx[r] = oi;
            }
        }
    }
    if (kg == 0) {
        #pragma unroll
        for (int r = 0; r < 8; ++r)
            idxf[rloc + r] = bidx[r];
    }
    __syncthreads();

    // ---- epilogue: q gather/store + loss; x read from LDS (same values).
    const int rt = t & 127;
    const int dg = t >> 7;            // 2 groups x 32 d (16 dp pairs)
    const int widx = idxf[rt];
    const float* wrow = w + widx * DIM + dg * 32;
    const float* xb = smem + dg * 16 * 256 + (rt >> 3) * 16 + (rt & 7) * 2;
    float* q = out + 1;
    float lsum = 0.0f;
    #pragma unroll
    for (int jj = 0; jj < 16; ++jj) {
        const int dE = dg * 32 + 2 * jj;
        const v2f wp2 = *(const v2f*)(wrow + 2 * jj);     // per-lane, L1-hot
        const v2f xp2 = *(const v2f*)(xb + jj * 256);     // (E,O) from LDS
        const float dfE = __fsub_rn(wp2[0], xp2[0]);      // d ascending: E,O
        lsum = __fadd_rn(lsum, __fmul_rn(dfE, dfE));
        const float dfO = __fsub_rn(wp2[1], xp2[1]);
        lsum = __fadd_rn(lsum, __fmul_rn(dfO, dfO));
        q[(size_t)(b * DIM + dE) * HW + hw0 + rt]     = wp2[0];
        q[(size_t)(b * DIM + dE + 1) * HW + hw0 + rt] = wp2[1];
    }

    #pragma unroll
    for (int off = 32; off; off >>= 1) lsum += __shfl_down(lsum, off, 64);
    if (lane == 0) lred[wv] = lsum;
    __syncthreads();
    if (t == 0)
        partial[blockIdx.x] = (lred[0] + lred[1]) + (lred[2] + lred[3]);

    // ---- encodings: direct compute, aligned float4 middle
    // (slab global float index == 1 mod 4 -> peel 3, tail 1).
    float* slab = out + 1 + (size_t)NROWS * DIM + (size_t)n0 * KCODES;
    if (t < 3) slab[t] = (idxf[0] == t) ? 1.0f : 0.0f;
    if (t == 4) slab[RPB * KCODES - 1] = (idxf[RPB - 1] == 511) ? 1.0f : 0.0f;
    {
        v4f* s4 = (v4f*)(slab + 3);                   // 16B-aligned
        const int nf4 = (RPB * KCODES - 4) / 4;       // 16383
        for (int f = t; f < nf4; f += TPB) {
            const int ii = 3 + 4 * f;
            v4f o;
            #pragma unroll
            for (int cc = 0; cc < 4; ++cc) {
                const int e = ii + cc;
                o[cc] = (idxf[e >> 9] == (e & 511)) ? 1.0f : 0.0f;
            }
            s4[f] = o;
        }
    }
}

__global__ __launch_bounds__(256) void vq_final(
    const float* __restrict__ partial, float* __restrict__ out)
{
    __shared__ float s[256];
    const int t = threadIdx.x;
    s[t] = partial[t] + partial[t + 256];
    __syncthreads();
    for (int off = 128; off; off >>= 1) {
        if (t < off) s[t] += s[t + off];
        __syncthreads();
    }
    if (t == 0) {
        const float m = s[0] / 4194304.0f;            // mean over B*H*W*D
        out[0] = __fadd_rn(m, __fmul_rn(0.25f, m));   // z_q + 0.25*z_e
    }
}

extern "C" void kernel_launch(void* const* d_in, const int* in_sizes, int n_in,
                              void* d_out, int out_size, void* d_ws, size_t ws_size,
                              hipStream_t stream) {
    const float* x = (const float*)d_in[0];
    const float* w = (const float*)d_in[1];
    float* out     = (float*)d_out;
    float* ws      = (float*)d_ws;

    // 73728 B dynamic LDS > 64 KB default limit: opt in (host-side,
    // idempotent, graph-capture-safe — not a stream op).
    (void)hipFuncSetAttribute((const void*)vq_main,
                              hipFuncAttributeMaxDynamicSharedMemorySize,
                              DYN_BYTES);

    vq_prep<<<2, 256, 0, stream>>>(w, ws);
    vq_main<<<NBLOCKS, TPB, DYN_BYTES, stream>>>(x, w, ws, out, ws + PART_OFF);
    vq_final<<<1, 256, 0, stream>>>(ws + PART_OFF, out);
}